// Round 1
// baseline (625.403 us; speedup 1.0000x reference)
//
#include <hip/hip_runtime.h>

// GCN 2-layer forward, fp32.
// Pipeline: deg -> dinv -> norm -> GEMM1 -> scatter1(atomic) -> GEMM2(+b1,relu)
//           -> scatter2(atomic) -> log_softmax
// ws layout (floats): deg[N] | norm[E] | h[N*128] | out1[N*128]
//   h region reused after scatter1: h2 = h[0..N*16), out2 = h[N*16..2*N*16)

__device__ inline void fma4(float4& a, float s, const float4& w) {
    a.x = fmaf(s, w.x, a.x);
    a.y = fmaf(s, w.y, a.y);
    a.z = fmaf(s, w.z, a.z);
    a.w = fmaf(s, w.w, a.w);
}

__global__ __launch_bounds__(256) void k_deg(const int* __restrict__ dst,
                                             float* __restrict__ deg, int E) {
    int e = blockIdx.x * 256 + threadIdx.x;
    if (e < E) unsafeAtomicAdd(&deg[dst[e]], 1.0f);
}

__global__ __launch_bounds__(256) void k_dinv(float* deg, int N) {
    int n = blockIdx.x * 256 + threadIdx.x;
    if (n < N) deg[n] = rsqrtf(fmaxf(deg[n], 1.0f));
}

__global__ __launch_bounds__(256) void k_norm(const int* __restrict__ src,
                                              const int* __restrict__ dst,
                                              const float* __restrict__ dinv,
                                              float* __restrict__ nrm, int E) {
    int e = blockIdx.x * 256 + threadIdx.x;
    if (e < E) nrm[e] = dinv[src[e]] * dinv[dst[e]];
}

// h[N,128] = x[N,128] @ W1[128,128]; 32-row tile/block, W1 staged in 2 col-halves.
__global__ __launch_bounds__(256) void k_gemm1(const float* __restrict__ x,
                                               const float* __restrict__ W,
                                               float* __restrict__ h, int N) {
    __shared__ float Wl[128 * 64];   // [k][c] one 64-col half, 32 KB
    __shared__ float xl[32 * 132];   // 32 rows, padded pitch 132 (bank spread), 16.9 KB
    int t = threadIdx.x;
    int row0 = blockIdx.x * 32;

    float4* xl4 = (float4*)xl;
    const float4* xg4 = (const float4*)x;
    for (int g = t; g < 32 * 32; g += 256) {
        int r = g >> 5, k4 = g & 31;
        float4 v = {0.f, 0.f, 0.f, 0.f};
        if (row0 + r < N) v = xg4[(size_t)(row0 + r) * 32 + k4];
        xl4[r * 33 + k4] = v;
    }

    float4* Wl4 = (float4*)Wl;
    const float4* Wg4 = (const float4*)W;
    int r = t >> 4;    // 0..15 -> rows r and r+16
    int cq = t & 15;   // col quad within the 64-col half

    for (int half = 0; half < 2; ++half) {
        __syncthreads();  // also covers xl staging on first pass
        for (int g = t; g < 128 * 16; g += 256) {
            int k = g >> 4, c4 = g & 15;
            Wl4[k * 16 + c4] = Wg4[k * 32 + half * 16 + c4];
        }
        __syncthreads();

        float4 a0 = {0.f, 0.f, 0.f, 0.f}, a1 = {0.f, 0.f, 0.f, 0.f};
        #pragma unroll 8
        for (int k4 = 0; k4 < 32; ++k4) {
            float4 xv0 = xl4[r * 33 + k4];
            float4 xv1 = xl4[(r + 16) * 33 + k4];
            float4 w0 = Wl4[(k4 * 4 + 0) * 16 + cq];
            float4 w1 = Wl4[(k4 * 4 + 1) * 16 + cq];
            float4 w2 = Wl4[(k4 * 4 + 2) * 16 + cq];
            float4 w3 = Wl4[(k4 * 4 + 3) * 16 + cq];
            fma4(a0, xv0.x, w0); fma4(a0, xv0.y, w1);
            fma4(a0, xv0.z, w2); fma4(a0, xv0.w, w3);
            fma4(a1, xv1.x, w0); fma4(a1, xv1.y, w1);
            fma4(a1, xv1.z, w2); fma4(a1, xv1.w, w3);
        }
        float4* hg4 = (float4*)h;
        if (row0 + r < N)
            hg4[(size_t)(row0 + r) * 32 + half * 16 + cq] = a0;
        if (row0 + r + 16 < N)
            hg4[(size_t)(row0 + r + 16) * 32 + half * 16 + cq] = a1;
    }
}

// out1[dst,f] += h[src,f]*norm[e]; idx = e*128+f; e is wave-uniform.
__global__ __launch_bounds__(256) void k_scatter1(const int* __restrict__ src,
                                                  const int* __restrict__ dst,
                                                  const float* __restrict__ nrm,
                                                  const float* __restrict__ h,
                                                  float* __restrict__ out1,
                                                  long long total) {
    long long idx = (long long)blockIdx.x * 256 + threadIdx.x;
    if (idx >= total) return;
    int e = __builtin_amdgcn_readfirstlane((int)(idx >> 7));
    int f = (int)(idx & 127);
    float v = h[(size_t)src[e] * 128 + f] * nrm[e];
    unsafeAtomicAdd(&out1[(size_t)dst[e] * 128 + f], v);
}

// h2[N,16] = relu(out1 + b1) @ W2[128,16]; 16-row tile/block.
__global__ __launch_bounds__(256) void k_gemm2(const float* __restrict__ out1,
                                               const float* __restrict__ b1,
                                               const float* __restrict__ W2,
                                               float* __restrict__ h2, int N) {
    __shared__ float W2T[16 * 128];  // [f][k]
    __shared__ float b1l[128];
    __shared__ float al[16 * 132];   // padded pitch
    int t = threadIdx.x;
    int row0 = blockIdx.x * 16;

    for (int g = t; g < 2048; g += 256) {
        int f = g >> 7, k = g & 127;
        W2T[f * 128 + k] = W2[k * 16 + f];
    }
    if (t < 128) b1l[t] = b1[t];
    __syncthreads();

    float4* al4 = (float4*)al;
    const float4* o4 = (const float4*)out1;
    const float4* b14 = (const float4*)b1l;
    for (int g = t; g < 16 * 32; g += 256) {
        int r = g >> 5, k4 = g & 31;
        float4 v = {0.f, 0.f, 0.f, 0.f};
        if (row0 + r < N) v = o4[(size_t)(row0 + r) * 32 + k4];
        float4 b = b14[k4];
        v.x = fmaxf(v.x + b.x, 0.f);
        v.y = fmaxf(v.y + b.y, 0.f);
        v.z = fmaxf(v.z + b.z, 0.f);
        v.w = fmaxf(v.w + b.w, 0.f);
        al4[r * 33 + k4] = v;
    }
    __syncthreads();

    int f = t & 15, r = t >> 4;
    const float4* W2T4 = (const float4*)W2T;
    float acc = 0.f;
    #pragma unroll 8
    for (int k4 = 0; k4 < 32; ++k4) {
        float4 av = al4[r * 33 + k4];
        float4 wv = W2T4[f * 32 + k4];
        acc = fmaf(av.x, wv.x, acc);
        acc = fmaf(av.y, wv.y, acc);
        acc = fmaf(av.z, wv.z, acc);
        acc = fmaf(av.w, wv.w, acc);
    }
    if (row0 + r < N) h2[(size_t)(row0 + r) * 16 + f] = acc;
}

__global__ __launch_bounds__(256) void k_scatter2(const int* __restrict__ src,
                                                  const int* __restrict__ dst,
                                                  const float* __restrict__ nrm,
                                                  const float* __restrict__ h2,
                                                  float* __restrict__ out2,
                                                  long long total) {
    long long idx = (long long)blockIdx.x * 256 + threadIdx.x;
    if (idx >= total) return;
    int e = (int)(idx >> 4);
    int f = (int)(idx & 15);
    float v = h2[(size_t)src[e] * 16 + f] * nrm[e];
    unsafeAtomicAdd(&out2[(size_t)dst[e] * 16 + f], v);
}

// out = log_softmax(out2 + b2) over 16 classes; 16-lane shuffle reduction.
__global__ __launch_bounds__(256) void k_final(const float* __restrict__ out2,
                                               const float* __restrict__ b2,
                                               float* __restrict__ out, int N) {
    int idx = blockIdx.x * 256 + threadIdx.x;
    if (idx >= N * 16) return;
    int f = idx & 15;
    float v = out2[idx] + b2[f];
    float m = v;
    #pragma unroll
    for (int off = 1; off < 16; off <<= 1) m = fmaxf(m, __shfl_xor(m, off));
    float s = expf(v - m);
    #pragma unroll
    for (int off = 1; off < 16; off <<= 1) s += __shfl_xor(s, off);
    out[idx] = v - m - logf(s);
}

extern "C" void kernel_launch(void* const* d_in, const int* in_sizes, int n_in,
                              void* d_out, int out_size, void* d_ws, size_t ws_size,
                              hipStream_t stream) {
    const float* x  = (const float*)d_in[0];
    const int*   ei = (const int*)d_in[1];
    const float* W1 = (const float*)d_in[2];
    const float* b1 = (const float*)d_in[3];
    const float* W2 = (const float*)d_in[4];
    const float* b2 = (const float*)d_in[5];
    float* out = (float*)d_out;

    const int E = in_sizes[1] / 2;
    const int N = in_sizes[0] / 128;
    const int* src = ei;
    const int* dstv = ei + E;

    float* deg  = (float*)d_ws;
    float* nrm  = deg + ((N + 3) & ~3);
    float* h    = nrm + ((E + 3) & ~3);
    float* out1 = h + (size_t)N * 128;
    float* h2   = h;                       // reuse after scatter1
    float* out2 = h + (size_t)N * 16;      // disjoint from h2

    hipMemsetAsync(deg, 0, (size_t)N * sizeof(float), stream);
    k_deg<<<(E + 255) / 256, 256, 0, stream>>>(dstv, deg, E);
    k_dinv<<<(N + 255) / 256, 256, 0, stream>>>(deg, N);
    k_norm<<<(E + 255) / 256, 256, 0, stream>>>(src, dstv, deg, nrm, E);

    k_gemm1<<<(N + 31) / 32, 256, 0, stream>>>(x, W1, h, N);

    hipMemsetAsync(out1, 0, (size_t)N * 128 * sizeof(float), stream);
    long long tot1 = (long long)E * 128;
    k_scatter1<<<(int)((tot1 + 255) / 256), 256, 0, stream>>>(src, dstv, nrm, h, out1, tot1);

    k_gemm2<<<(N + 15) / 16, 256, 0, stream>>>(out1, b1, W2, h2, N);

    hipMemsetAsync(out2, 0, (size_t)N * 16 * sizeof(float), stream);
    long long tot2 = (long long)E * 16;
    k_scatter2<<<(int)((tot2 + 255) / 256), 256, 0, stream>>>(src, dstv, nrm, h2, out2, tot2);

    k_final<<<(N * 16 + 255) / 256, 256, 0, stream>>>(out2, b2, out, N);
}

// Round 2
// 346.418 us; speedup vs baseline: 1.8053x; 1.8053x over previous
//
#include <hip/hip_runtime.h>

// GCN 2-layer forward, fp32 — pull-based aggregation (no atomics in hot loops).
// Pipeline: count(hist) -> dinv -> scan(3) -> place(sort edges by dst)
//           -> GEMM1 -> pull1 -> GEMM2(+b1,relu) -> pull2 -> log_softmax
// CSR trick: after k_place, rs[n] = row_start(n+1); row n spans
//            [n?rs[n-1]:0, rs[n]).  norm recomputed on the fly from dinv.

__device__ inline void fma4(float4& a, float s, const float4& w) {
    a.x = fmaf(s, w.x, a.x);
    a.y = fmaf(s, w.y, a.y);
    a.z = fmaf(s, w.z, a.z);
    a.w = fmaf(s, w.w, a.w);
}

__global__ __launch_bounds__(256) void k_count(const int* __restrict__ dst,
                                               int* __restrict__ cnt, int E) {
    int e = blockIdx.x * 256 + threadIdx.x;
    if (e < E) atomicAdd(&cnt[dst[e]], 1);
}

__global__ __launch_bounds__(256) void k_dinv(const int* __restrict__ cnt,
                                              float* __restrict__ dinv, int N) {
    int n = blockIdx.x * 256 + threadIdx.x;
    if (n < N) dinv[n] = rsqrtf(fmaxf((float)cnt[n], 1.0f));
}

// exclusive scan of cnt[N] into rs[N]; aux[b] = block total
__global__ __launch_bounds__(256) void k_scan1(const int* __restrict__ cnt,
                                               int* __restrict__ rs,
                                               int* __restrict__ aux, int N) {
    __shared__ int s[256];
    int t = threadIdx.x;
    int i = blockIdx.x * 256 + t;
    int v = (i < N) ? cnt[i] : 0;
    s[t] = v;
    __syncthreads();
    for (int off = 1; off < 256; off <<= 1) {
        int u = (t >= off) ? s[t - off] : 0;
        __syncthreads();
        s[t] += u;
        __syncthreads();
    }
    if (i < N) rs[i] = s[t] - v;
    if (t == 255) aux[blockIdx.x] = s[255];
}

__global__ void k_scan2(int* __restrict__ aux, int nb) {
    __shared__ int s[256];
    int t = threadIdx.x;
    int v = (t < nb) ? aux[t] : 0;
    s[t] = v;
    __syncthreads();
    for (int off = 1; off < 256; off <<= 1) {
        int u = (t >= off) ? s[t - off] : 0;
        __syncthreads();
        s[t] += u;
        __syncthreads();
    }
    if (t < nb) aux[t] = s[t] - v;
}

__global__ __launch_bounds__(256) void k_scan3(int* __restrict__ rs,
                                               const int* __restrict__ aux, int N) {
    int i = blockIdx.x * 256 + threadIdx.x;
    if (i < N) rs[i] += aux[blockIdx.x];
}

// place edges sorted by dst; afterwards rs[n] = row_start(n+1)
__global__ __launch_bounds__(256) void k_place(const int* __restrict__ src,
                                               const int* __restrict__ dst,
                                               int* __restrict__ rs,
                                               int* __restrict__ ssrc, int E) {
    int e = blockIdx.x * 256 + threadIdx.x;
    if (e < E) {
        int pos = atomicAdd(&rs[dst[e]], 1);
        ssrc[pos] = src[e];
    }
}

// h[N,128] = x[N,128] @ W1[128,128]; 32-row tile/block, W1 staged in 2 col-halves.
__global__ __launch_bounds__(256) void k_gemm1(const float* __restrict__ x,
                                               const float* __restrict__ W,
                                               float* __restrict__ h, int N) {
    __shared__ float Wl[128 * 64];
    __shared__ float xl[32 * 132];
    int t = threadIdx.x;
    int row0 = blockIdx.x * 32;

    float4* xl4 = (float4*)xl;
    const float4* xg4 = (const float4*)x;
    for (int g = t; g < 32 * 32; g += 256) {
        int r = g >> 5, k4 = g & 31;
        float4 v = {0.f, 0.f, 0.f, 0.f};
        if (row0 + r < N) v = xg4[(size_t)(row0 + r) * 32 + k4];
        xl4[r * 33 + k4] = v;
    }

    float4* Wl4 = (float4*)Wl;
    const float4* Wg4 = (const float4*)W;
    int r = t >> 4;
    int cq = t & 15;

    for (int half = 0; half < 2; ++half) {
        __syncthreads();
        for (int g = t; g < 128 * 16; g += 256) {
            int k = g >> 4, c4 = g & 15;
            Wl4[k * 16 + c4] = Wg4[k * 32 + half * 16 + c4];
        }
        __syncthreads();

        float4 a0 = {0.f, 0.f, 0.f, 0.f}, a1 = {0.f, 0.f, 0.f, 0.f};
        #pragma unroll 8
        for (int k4 = 0; k4 < 32; ++k4) {
            float4 xv0 = xl4[r * 33 + k4];
            float4 xv1 = xl4[(r + 16) * 33 + k4];
            float4 w0 = Wl4[(k4 * 4 + 0) * 16 + cq];
            float4 w1 = Wl4[(k4 * 4 + 1) * 16 + cq];
            float4 w2 = Wl4[(k4 * 4 + 2) * 16 + cq];
            float4 w3 = Wl4[(k4 * 4 + 3) * 16 + cq];
            fma4(a0, xv0.x, w0); fma4(a0, xv0.y, w1);
            fma4(a0, xv0.z, w2); fma4(a0, xv0.w, w3);
            fma4(a1, xv1.x, w0); fma4(a1, xv1.y, w1);
            fma4(a1, xv1.z, w2); fma4(a1, xv1.w, w3);
        }
        float4* hg4 = (float4*)h;
        if (row0 + r < N)
            hg4[(size_t)(row0 + r) * 32 + half * 16 + cq] = a0;
        if (row0 + r + 16 < N)
            hg4[(size_t)(row0 + r + 16) * 32 + half * 16 + cq] = a1;
    }
}

// out1[n,:] = sum_{e in row n} dinv[n]*dinv[src]*h[src,:]; one wave per row.
__global__ __launch_bounds__(256) void k_pull1(const int* __restrict__ rs,
                                               const int* __restrict__ ssrc,
                                               const float* __restrict__ dinv,
                                               const float* __restrict__ h,
                                               float* __restrict__ out1, int N) {
    int n = (blockIdx.x * 256 + threadIdx.x) >> 6;
    if (n >= N) return;
    int lane = threadIdx.x & 63;
    int start = __builtin_amdgcn_readfirstlane((n == 0) ? 0 : rs[n - 1]);
    int end   = __builtin_amdgcn_readfirstlane(rs[n]);
    float dn = dinv[n];
    const float2* hp = (const float2*)h;
    float2 a0 = {0.f, 0.f}, a1 = {0.f, 0.f};
    int j = start;
    for (; j + 1 < end; j += 2) {
        int s0 = __builtin_amdgcn_readfirstlane(ssrc[j]);
        int s1 = __builtin_amdgcn_readfirstlane(ssrc[j + 1]);
        float w0 = dn * dinv[s0];
        float w1 = dn * dinv[s1];
        float2 v0 = hp[(size_t)s0 * 64 + lane];
        float2 v1 = hp[(size_t)s1 * 64 + lane];
        a0.x = fmaf(w0, v0.x, a0.x); a0.y = fmaf(w0, v0.y, a0.y);
        a1.x = fmaf(w1, v1.x, a1.x); a1.y = fmaf(w1, v1.y, a1.y);
    }
    if (j < end) {
        int s0 = __builtin_amdgcn_readfirstlane(ssrc[j]);
        float w0 = dn * dinv[s0];
        float2 v0 = hp[(size_t)s0 * 64 + lane];
        a0.x = fmaf(w0, v0.x, a0.x); a0.y = fmaf(w0, v0.y, a0.y);
    }
    float2 r;
    r.x = a0.x + a1.x;
    r.y = a0.y + a1.y;
    ((float2*)out1)[(size_t)n * 64 + lane] = r;
}

// h2[N,16] = relu(out1 + b1) @ W2[128,16]; 16-row tile/block.
__global__ __launch_bounds__(256) void k_gemm2(const float* __restrict__ out1,
                                               const float* __restrict__ b1,
                                               const float* __restrict__ W2,
                                               float* __restrict__ h2, int N) {
    __shared__ float W2T[16 * 128];
    __shared__ float b1l[128];
    __shared__ float al[16 * 132];
    int t = threadIdx.x;
    int row0 = blockIdx.x * 16;

    for (int g = t; g < 2048; g += 256) {
        int f = g >> 7, k = g & 127;
        W2T[f * 128 + k] = W2[k * 16 + f];
    }
    if (t < 128) b1l[t] = b1[t];
    __syncthreads();

    float4* al4 = (float4*)al;
    const float4* o4 = (const float4*)out1;
    const float4* b14 = (const float4*)b1l;
    for (int g = t; g < 16 * 32; g += 256) {
        int r = g >> 5, k4 = g & 31;
        float4 v = {0.f, 0.f, 0.f, 0.f};
        if (row0 + r < N) v = o4[(size_t)(row0 + r) * 32 + k4];
        float4 b = b14[k4];
        v.x = fmaxf(v.x + b.x, 0.f);
        v.y = fmaxf(v.y + b.y, 0.f);
        v.z = fmaxf(v.z + b.z, 0.f);
        v.w = fmaxf(v.w + b.w, 0.f);
        al4[r * 33 + k4] = v;
    }
    __syncthreads();

    int f = t & 15, r = t >> 4;
    const float4* W2T4 = (const float4*)W2T;
    float acc = 0.f;
    #pragma unroll 8
    for (int k4 = 0; k4 < 32; ++k4) {
        float4 av = al4[r * 33 + k4];
        float4 wv = W2T4[f * 32 + k4];
        acc = fmaf(av.x, wv.x, acc);
        acc = fmaf(av.y, wv.y, acc);
        acc = fmaf(av.z, wv.z, acc);
        acc = fmaf(av.w, wv.w, acc);
    }
    if (row0 + r < N) h2[(size_t)(row0 + r) * 16 + f] = acc;
}

// out2[n,f] = sum_{e in row n} dinv[n]*dinv[src]*h2[src,f]; 16 lanes per row.
__global__ __launch_bounds__(256) void k_pull2(const int* __restrict__ rs,
                                               const int* __restrict__ ssrc,
                                               const float* __restrict__ dinv,
                                               const float* __restrict__ h2,
                                               float* __restrict__ out2, int N) {
    int idx = blockIdx.x * 256 + threadIdx.x;
    int n = idx >> 4;
    if (n >= N) return;
    int f = idx & 15;
    int start = (n == 0) ? 0 : rs[n - 1];
    int end = rs[n];
    float dn = dinv[n];
    float acc = 0.f;
    for (int j = start; j < end; ++j) {
        int s = ssrc[j];
        acc = fmaf(dn * dinv[s], h2[(size_t)s * 16 + f], acc);
    }
    out2[idx] = acc;
}

// out = log_softmax(out2 + b2) over 16 classes; 16-lane shuffle reduction.
__global__ __launch_bounds__(256) void k_final(const float* __restrict__ out2,
                                               const float* __restrict__ b2,
                                               float* __restrict__ out, int N) {
    int idx = blockIdx.x * 256 + threadIdx.x;
    if (idx >= N * 16) return;
    int f = idx & 15;
    float v = out2[idx] + b2[f];
    float m = v;
    #pragma unroll
    for (int off = 1; off < 16; off <<= 1) m = fmaxf(m, __shfl_xor(m, off));
    float s = expf(v - m);
    #pragma unroll
    for (int off = 1; off < 16; off <<= 1) s += __shfl_xor(s, off);
    out[idx] = v - m - logf(s);
}

extern "C" void kernel_launch(void* const* d_in, const int* in_sizes, int n_in,
                              void* d_out, int out_size, void* d_ws, size_t ws_size,
                              hipStream_t stream) {
    const float* x  = (const float*)d_in[0];
    const int*   ei = (const int*)d_in[1];
    const float* W1 = (const float*)d_in[2];
    const float* b1 = (const float*)d_in[3];
    const float* W2 = (const float*)d_in[4];
    const float* b2 = (const float*)d_in[5];
    float* out = (float*)d_out;

    const int E = in_sizes[1] / 2;
    const int N = in_sizes[0] / 128;
    const int* src  = ei;
    const int* dstv = ei + E;

    const int Npad = (N + 255) & ~255;
    int*   cnt  = (int*)d_ws;
    int*   rs   = cnt + Npad;
    int*   aux  = rs + Npad;
    float* dinv = (float*)(aux + 256);
    int*   ssrc = (int*)(dinv + Npad);
    float* h    = (float*)(ssrc + ((E + 255) & ~255));
    float* out1 = h + (size_t)N * 128;
    float* h2   = h;                   // reuse after pull1
    float* out2 = h + (size_t)N * 16;  // disjoint from h2

    const int nbN = (N + 255) / 256;
    const int nbE = (E + 255) / 256;

    hipMemsetAsync(cnt, 0, (size_t)N * sizeof(int), stream);
    k_count<<<nbE, 256, 0, stream>>>(dstv, cnt, E);
    k_dinv<<<nbN, 256, 0, stream>>>(cnt, dinv, N);
    k_scan1<<<nbN, 256, 0, stream>>>(cnt, rs, aux, N);
    k_scan2<<<1, 256, 0, stream>>>(aux, nbN);
    k_scan3<<<nbN, 256, 0, stream>>>(rs, aux, N);
    k_place<<<nbE, 256, 0, stream>>>(src, dstv, rs, ssrc, E);

    k_gemm1<<<(N + 31) / 32, 256, 0, stream>>>(x, W1, h, N);

    k_pull1<<<(N * 64 + 255) / 256, 256, 0, stream>>>(rs, ssrc, dinv, h, out1, N);

    k_gemm2<<<(N + 15) / 16, 256, 0, stream>>>(out1, b1, W2, h2, N);

    k_pull2<<<(N * 16 + 255) / 256, 256, 0, stream>>>(rs, ssrc, dinv, h2, out2, N);

    k_final<<<(N * 16 + 255) / 256, 256, 0, stream>>>(out2, b2, out, N);
}

// Round 3
// 301.623 us; speedup vs baseline: 2.0735x; 1.1485x over previous
//
#include <hip/hip_runtime.h>

// GCN 2-layer forward, fp32 — pull-based aggregation (no atomics in hot loops).
// Pipeline: count(hist) -> dinv -> scan(3) -> place(sort edges by dst)
//           -> GEMM1 -> pull1 -> GEMM2(+b1,relu) -> pull2+log_softmax (fused)
// CSR trick: after k_place, rs[n] = row_start(n+1); row n spans
//            [n?rs[n-1]:0, rs[n]).  norm recomputed on the fly from dinv.
// R3: gemm2 LDS pitch 132 (was 128 -> 16-way bank conflict, 2.4e7 cycles),
//     2 rows/thread; log_softmax fused into pull2.

__device__ inline void fma4(float4& a, float s, const float4& w) {
    a.x = fmaf(s, w.x, a.x);
    a.y = fmaf(s, w.y, a.y);
    a.z = fmaf(s, w.z, a.z);
    a.w = fmaf(s, w.w, a.w);
}

__global__ __launch_bounds__(256) void k_count(const int* __restrict__ dst,
                                               int* __restrict__ cnt, int E) {
    int e = blockIdx.x * 256 + threadIdx.x;
    if (e < E) atomicAdd(&cnt[dst[e]], 1);
}

__global__ __launch_bounds__(256) void k_dinv(const int* __restrict__ cnt,
                                              float* __restrict__ dinv, int N) {
    int n = blockIdx.x * 256 + threadIdx.x;
    if (n < N) dinv[n] = rsqrtf(fmaxf((float)cnt[n], 1.0f));
}

// exclusive scan of cnt[N] into rs[N]; aux[b] = block total
__global__ __launch_bounds__(256) void k_scan1(const int* __restrict__ cnt,
                                               int* __restrict__ rs,
                                               int* __restrict__ aux, int N) {
    __shared__ int s[256];
    int t = threadIdx.x;
    int i = blockIdx.x * 256 + t;
    int v = (i < N) ? cnt[i] : 0;
    s[t] = v;
    __syncthreads();
    for (int off = 1; off < 256; off <<= 1) {
        int u = (t >= off) ? s[t - off] : 0;
        __syncthreads();
        s[t] += u;
        __syncthreads();
    }
    if (i < N) rs[i] = s[t] - v;
    if (t == 255) aux[blockIdx.x] = s[255];
}

__global__ void k_scan2(int* __restrict__ aux, int nb) {
    __shared__ int s[256];
    int t = threadIdx.x;
    int v = (t < nb) ? aux[t] : 0;
    s[t] = v;
    __syncthreads();
    for (int off = 1; off < 256; off <<= 1) {
        int u = (t >= off) ? s[t - off] : 0;
        __syncthreads();
        s[t] += u;
        __syncthreads();
    }
    if (t < nb) aux[t] = s[t] - v;
}

__global__ __launch_bounds__(256) void k_scan3(int* __restrict__ rs,
                                               const int* __restrict__ aux, int N) {
    int i = blockIdx.x * 256 + threadIdx.x;
    if (i < N) rs[i] += aux[blockIdx.x];
}

// place edges sorted by dst; afterwards rs[n] = row_start(n+1)
__global__ __launch_bounds__(256) void k_place(const int* __restrict__ src,
                                               const int* __restrict__ dst,
                                               int* __restrict__ rs,
                                               int* __restrict__ ssrc, int E) {
    int e = blockIdx.x * 256 + threadIdx.x;
    if (e < E) {
        int pos = atomicAdd(&rs[dst[e]], 1);
        ssrc[pos] = src[e];
    }
}

// h[N,128] = x[N,128] @ W1[128,128]; 32-row tile/block, W1 staged in 2 col-halves.
__global__ __launch_bounds__(256) void k_gemm1(const float* __restrict__ x,
                                               const float* __restrict__ W,
                                               float* __restrict__ h, int N) {
    __shared__ float Wl[128 * 64];
    __shared__ float xl[32 * 132];
    int t = threadIdx.x;
    int row0 = blockIdx.x * 32;

    float4* xl4 = (float4*)xl;
    const float4* xg4 = (const float4*)x;
    for (int g = t; g < 32 * 32; g += 256) {
        int r = g >> 5, k4 = g & 31;
        float4 v = {0.f, 0.f, 0.f, 0.f};
        if (row0 + r < N) v = xg4[(size_t)(row0 + r) * 32 + k4];
        xl4[r * 33 + k4] = v;
    }

    float4* Wl4 = (float4*)Wl;
    const float4* Wg4 = (const float4*)W;
    int r = t >> 4;
    int cq = t & 15;

    for (int half = 0; half < 2; ++half) {
        __syncthreads();
        for (int g = t; g < 128 * 16; g += 256) {
            int k = g >> 4, c4 = g & 15;
            Wl4[k * 16 + c4] = Wg4[k * 32 + half * 16 + c4];
        }
        __syncthreads();

        float4 a0 = {0.f, 0.f, 0.f, 0.f}, a1 = {0.f, 0.f, 0.f, 0.f};
        #pragma unroll 8
        for (int k4 = 0; k4 < 32; ++k4) {
            float4 xv0 = xl4[r * 33 + k4];
            float4 xv1 = xl4[(r + 16) * 33 + k4];
            float4 w0 = Wl4[(k4 * 4 + 0) * 16 + cq];
            float4 w1 = Wl4[(k4 * 4 + 1) * 16 + cq];
            float4 w2 = Wl4[(k4 * 4 + 2) * 16 + cq];
            float4 w3 = Wl4[(k4 * 4 + 3) * 16 + cq];
            fma4(a0, xv0.x, w0); fma4(a0, xv0.y, w1);
            fma4(a0, xv0.z, w2); fma4(a0, xv0.w, w3);
            fma4(a1, xv1.x, w0); fma4(a1, xv1.y, w1);
            fma4(a1, xv1.z, w2); fma4(a1, xv1.w, w3);
        }
        float4* hg4 = (float4*)h;
        if (row0 + r < N)
            hg4[(size_t)(row0 + r) * 32 + half * 16 + cq] = a0;
        if (row0 + r + 16 < N)
            hg4[(size_t)(row0 + r + 16) * 32 + half * 16 + cq] = a1;
    }
}

// out1[n,:] = sum_{e in row n} dinv[n]*dinv[src]*h[src,:]; one wave per row.
__global__ __launch_bounds__(256) void k_pull1(const int* __restrict__ rs,
                                               const int* __restrict__ ssrc,
                                               const float* __restrict__ dinv,
                                               const float* __restrict__ h,
                                               float* __restrict__ out1, int N) {
    int n = (blockIdx.x * 256 + threadIdx.x) >> 6;
    if (n >= N) return;
    int lane = threadIdx.x & 63;
    int start = __builtin_amdgcn_readfirstlane((n == 0) ? 0 : rs[n - 1]);
    int end   = __builtin_amdgcn_readfirstlane(rs[n]);
    float dn = dinv[n];
    const float2* hp = (const float2*)h;
    float2 a0 = {0.f, 0.f}, a1 = {0.f, 0.f};
    int j = start;
    for (; j + 1 < end; j += 2) {
        int s0 = __builtin_amdgcn_readfirstlane(ssrc[j]);
        int s1 = __builtin_amdgcn_readfirstlane(ssrc[j + 1]);
        float w0 = dn * dinv[s0];
        float w1 = dn * dinv[s1];
        float2 v0 = hp[(size_t)s0 * 64 + lane];
        float2 v1 = hp[(size_t)s1 * 64 + lane];
        a0.x = fmaf(w0, v0.x, a0.x); a0.y = fmaf(w0, v0.y, a0.y);
        a1.x = fmaf(w1, v1.x, a1.x); a1.y = fmaf(w1, v1.y, a1.y);
    }
    if (j < end) {
        int s0 = __builtin_amdgcn_readfirstlane(ssrc[j]);
        float w0 = dn * dinv[s0];
        float2 v0 = hp[(size_t)s0 * 64 + lane];
        a0.x = fmaf(w0, v0.x, a0.x); a0.y = fmaf(w0, v0.y, a0.y);
    }
    float2 r;
    r.x = a0.x + a1.x;
    r.y = a0.y + a1.y;
    ((float2*)out1)[(size_t)n * 64 + lane] = r;
}

// h2[N,16] = relu(out1 + b1) @ W2[128,16]; 32-row tile/block, 2 rows/thread.
// LDS pitch 132 floats (33 float4): W2 reads 2-way (free), x reads 4-addr clean.
__global__ __launch_bounds__(256) void k_gemm2(const float* __restrict__ out1,
                                               const float* __restrict__ b1,
                                               const float* __restrict__ W2,
                                               float* __restrict__ h2, int N) {
    __shared__ float W2T[16 * 132];  // [f][k], pitch 132
    __shared__ float b1l[128];
    __shared__ float al[32 * 132];   // 32 rows, pitch 132
    int t = threadIdx.x;
    int row0 = blockIdx.x * 32;

    for (int g = t; g < 2048; g += 256) {
        int k = g >> 4, f = g & 15;          // coalesced global read of W2[k][f]
        W2T[f * 132 + k] = W2[g];
    }
    if (t < 128) b1l[t] = b1[t];
    __syncthreads();

    float4* al4 = (float4*)al;
    const float4* o4 = (const float4*)out1;
    const float4* b14 = (const float4*)b1l;
    for (int g = t; g < 32 * 32; g += 256) {
        int r = g >> 5, k4 = g & 31;
        float4 v = {0.f, 0.f, 0.f, 0.f};
        if (row0 + r < N) v = o4[(size_t)(row0 + r) * 32 + k4];
        float4 b = b14[k4];
        v.x = fmaxf(v.x + b.x, 0.f);
        v.y = fmaxf(v.y + b.y, 0.f);
        v.z = fmaxf(v.z + b.z, 0.f);
        v.w = fmaxf(v.w + b.w, 0.f);
        al4[r * 33 + k4] = v;
    }
    __syncthreads();

    int f = t & 15, r0 = t >> 4;             // rows r0 and r0+16
    const float4* W4 = (const float4*)W2T;   // pitch 33
    float acc0 = 0.f, acc1 = 0.f;
    #pragma unroll 8
    for (int k4 = 0; k4 < 32; ++k4) {
        float4 w  = W4[f * 33 + k4];
        float4 x0 = al4[r0 * 33 + k4];
        float4 x1 = al4[(r0 + 16) * 33 + k4];
        acc0 = fmaf(x0.x, w.x, acc0); acc0 = fmaf(x0.y, w.y, acc0);
        acc0 = fmaf(x0.z, w.z, acc0); acc0 = fmaf(x0.w, w.w, acc0);
        acc1 = fmaf(x1.x, w.x, acc1); acc1 = fmaf(x1.y, w.y, acc1);
        acc1 = fmaf(x1.z, w.z, acc1); acc1 = fmaf(x1.w, w.w, acc1);
    }
    if (row0 + r0 < N)      h2[(size_t)(row0 + r0) * 16 + f] = acc0;
    if (row0 + r0 + 16 < N) h2[(size_t)(row0 + r0 + 16) * 16 + f] = acc1;
}

// out[n,f] = log_softmax_f( b2[f] + sum_{e in row n} dinv[n]*dinv[src]*h2[src,f] )
// 16 lanes per row; softmax via 16-lane shuffle reduction (fused epilogue).
__global__ __launch_bounds__(256) void k_pull2(const int* __restrict__ rs,
                                               const int* __restrict__ ssrc,
                                               const float* __restrict__ dinv,
                                               const float* __restrict__ h2,
                                               const float* __restrict__ b2,
                                               float* __restrict__ out, int N) {
    int idx = blockIdx.x * 256 + threadIdx.x;
    int n = idx >> 4;
    if (n >= N) return;
    int f = idx & 15;
    int start = (n == 0) ? 0 : rs[n - 1];
    int end = rs[n];
    float dn = dinv[n];
    float acc = 0.f;
    for (int j = start; j < end; ++j) {
        int s = ssrc[j];
        acc = fmaf(dn * dinv[s], h2[(size_t)s * 16 + f], acc);
    }
    float v = acc + b2[f];
    float m = v;
    #pragma unroll
    for (int off = 1; off < 16; off <<= 1) m = fmaxf(m, __shfl_xor(m, off));
    float s = expf(v - m);
    #pragma unroll
    for (int off = 1; off < 16; off <<= 1) s += __shfl_xor(s, off);
    out[idx] = v - m - logf(s);
}

extern "C" void kernel_launch(void* const* d_in, const int* in_sizes, int n_in,
                              void* d_out, int out_size, void* d_ws, size_t ws_size,
                              hipStream_t stream) {
    const float* x  = (const float*)d_in[0];
    const int*   ei = (const int*)d_in[1];
    const float* W1 = (const float*)d_in[2];
    const float* b1 = (const float*)d_in[3];
    const float* W2 = (const float*)d_in[4];
    const float* b2 = (const float*)d_in[5];
    float* out = (float*)d_out;

    const int E = in_sizes[1] / 2;
    const int N = in_sizes[0] / 128;
    const int* src  = ei;
    const int* dstv = ei + E;

    const int Npad = (N + 255) & ~255;
    int*   cnt  = (int*)d_ws;
    int*   rs   = cnt + Npad;
    int*   aux  = rs + Npad;
    float* dinv = (float*)(aux + 256);
    int*   ssrc = (int*)(dinv + Npad);
    float* h    = (float*)(ssrc + ((E + 255) & ~255));
    float* out1 = h + (size_t)N * 128;
    float* h2   = h;  // reuse after pull1

    const int nbN = (N + 255) / 256;
    const int nbE = (E + 255) / 256;

    hipMemsetAsync(cnt, 0, (size_t)N * sizeof(int), stream);
    k_count<<<nbE, 256, 0, stream>>>(dstv, cnt, E);
    k_dinv<<<nbN, 256, 0, stream>>>(cnt, dinv, N);
    k_scan1<<<nbN, 256, 0, stream>>>(cnt, rs, aux, N);
    k_scan2<<<1, 256, 0, stream>>>(aux, nbN);
    k_scan3<<<nbN, 256, 0, stream>>>(rs, aux, N);
    k_place<<<nbE, 256, 0, stream>>>(src, dstv, rs, ssrc, E);

    k_gemm1<<<(N + 31) / 32, 256, 0, stream>>>(x, W1, h, N);

    k_pull1<<<(N * 64 + 255) / 256, 256, 0, stream>>>(rs, ssrc, dinv, h, out1, N);

    k_gemm2<<<(N + 31) / 32, 256, 0, stream>>>(out1, b1, W2, h2, N);

    k_pull2<<<(N * 16 + 255) / 256, 256, 0, stream>>>(rs, ssrc, dinv, h2, b2, out, N);
}

// Round 4
// 269.718 us; speedup vs baseline: 2.3187x; 1.1183x over previous
//
#include <hip/hip_runtime.h>

// GCN 2-layer forward — pull-based aggregation, bf16 gather payloads.
// Pipeline: count(hist) -> dinv -> scan(3) -> place(sort edges by dst)
//           -> GEMM1(->bf16 h) -> pull1 -> GEMM2(+b1,relu,->bf16 h2)
//           -> pull2+log_softmax (fused)
// R4: h and h2 stored bf16 (fp32 accumulate). h gather: 256B/row (was 512);
//     per-XCD L2 refetch of h halves; h2 (1.6MB) now fits a 4MB XCD L2.
//     pull1 unrolled 4-deep for memory-level parallelism.

typedef unsigned int uint32;
typedef unsigned short ushort16;

__device__ inline void fma4(float4& a, float s, const float4& w) {
    a.x = fmaf(s, w.x, a.x);
    a.y = fmaf(s, w.y, a.y);
    a.z = fmaf(s, w.z, a.z);
    a.w = fmaf(s, w.w, a.w);
}

__device__ inline unsigned short bf16rn(float f) {
    unsigned u = __float_as_uint(f);
    return (unsigned short)((u + 0x7fffu + ((u >> 16) & 1u)) >> 16);
}

// fma of packed bf16x2 (u) by scalar w into float2 acc
__device__ inline void bffma(float2& a, float w, uint32 u) {
    a.x = fmaf(w, __uint_as_float(u << 16), a.x);
    a.y = fmaf(w, __uint_as_float(u & 0xffff0000u), a.y);
}

__global__ __launch_bounds__(256) void k_count(const int* __restrict__ dst,
                                               int* __restrict__ cnt, int E) {
    int e = blockIdx.x * 256 + threadIdx.x;
    if (e < E) atomicAdd(&cnt[dst[e]], 1);
}

__global__ __launch_bounds__(256) void k_dinv(const int* __restrict__ cnt,
                                              float* __restrict__ dinv, int N) {
    int n = blockIdx.x * 256 + threadIdx.x;
    if (n < N) dinv[n] = rsqrtf(fmaxf((float)cnt[n], 1.0f));
}

__global__ __launch_bounds__(256) void k_scan1(const int* __restrict__ cnt,
                                               int* __restrict__ rs,
                                               int* __restrict__ aux, int N) {
    __shared__ int s[256];
    int t = threadIdx.x;
    int i = blockIdx.x * 256 + t;
    int v = (i < N) ? cnt[i] : 0;
    s[t] = v;
    __syncthreads();
    for (int off = 1; off < 256; off <<= 1) {
        int u = (t >= off) ? s[t - off] : 0;
        __syncthreads();
        s[t] += u;
        __syncthreads();
    }
    if (i < N) rs[i] = s[t] - v;
    if (t == 255) aux[blockIdx.x] = s[255];
}

__global__ void k_scan2(int* __restrict__ aux, int nb) {
    __shared__ int s[256];
    int t = threadIdx.x;
    int v = (t < nb) ? aux[t] : 0;
    s[t] = v;
    __syncthreads();
    for (int off = 1; off < 256; off <<= 1) {
        int u = (t >= off) ? s[t - off] : 0;
        __syncthreads();
        s[t] += u;
        __syncthreads();
    }
    if (t < nb) aux[t] = s[t] - v;
}

__global__ __launch_bounds__(256) void k_scan3(int* __restrict__ rs,
                                               const int* __restrict__ aux, int N) {
    int i = blockIdx.x * 256 + threadIdx.x;
    if (i < N) rs[i] += aux[blockIdx.x];
}

__global__ __launch_bounds__(256) void k_place(const int* __restrict__ src,
                                               const int* __restrict__ dst,
                                               int* __restrict__ rs,
                                               int* __restrict__ ssrc, int E) {
    int e = blockIdx.x * 256 + threadIdx.x;
    if (e < E) {
        int pos = atomicAdd(&rs[dst[e]], 1);
        ssrc[pos] = src[e];
    }
}

// h[N,128](bf16) = x[N,128] @ W1[128,128]; 32-row tile, W1 in 2 col-halves.
__global__ __launch_bounds__(256) void k_gemm1(const float* __restrict__ x,
                                               const float* __restrict__ W,
                                               ushort16* __restrict__ h, int N) {
    __shared__ float Wl[128 * 64];
    __shared__ float xl[32 * 132];
    int t = threadIdx.x;
    int row0 = blockIdx.x * 32;

    float4* xl4 = (float4*)xl;
    const float4* xg4 = (const float4*)x;
    for (int g = t; g < 32 * 32; g += 256) {
        int r = g >> 5, k4 = g & 31;
        float4 v = {0.f, 0.f, 0.f, 0.f};
        if (row0 + r < N) v = xg4[(size_t)(row0 + r) * 32 + k4];
        xl4[r * 33 + k4] = v;
    }

    float4* Wl4 = (float4*)Wl;
    const float4* Wg4 = (const float4*)W;
    int r = t >> 4;
    int cq = t & 15;

    for (int half = 0; half < 2; ++half) {
        __syncthreads();
        for (int g = t; g < 128 * 16; g += 256) {
            int k = g >> 4, c4 = g & 15;
            Wl4[k * 16 + c4] = Wg4[k * 32 + half * 16 + c4];
        }
        __syncthreads();

        float4 a0 = {0.f, 0.f, 0.f, 0.f}, a1 = {0.f, 0.f, 0.f, 0.f};
        #pragma unroll 8
        for (int k4 = 0; k4 < 32; ++k4) {
            float4 xv0 = xl4[r * 33 + k4];
            float4 xv1 = xl4[(r + 16) * 33 + k4];
            float4 w0 = Wl4[(k4 * 4 + 0) * 16 + cq];
            float4 w1 = Wl4[(k4 * 4 + 1) * 16 + cq];
            float4 w2 = Wl4[(k4 * 4 + 2) * 16 + cq];
            float4 w3 = Wl4[(k4 * 4 + 3) * 16 + cq];
            fma4(a0, xv0.x, w0); fma4(a0, xv0.y, w1);
            fma4(a0, xv0.z, w2); fma4(a0, xv0.w, w3);
            fma4(a1, xv1.x, w0); fma4(a1, xv1.y, w1);
            fma4(a1, xv1.z, w2); fma4(a1, xv1.w, w3);
        }
        ushort4 p0, p1;
        p0.x = bf16rn(a0.x); p0.y = bf16rn(a0.y); p0.z = bf16rn(a0.z); p0.w = bf16rn(a0.w);
        p1.x = bf16rn(a1.x); p1.y = bf16rn(a1.y); p1.z = bf16rn(a1.z); p1.w = bf16rn(a1.w);
        if (row0 + r < N)
            *(ushort4*)(h + (size_t)(row0 + r) * 128 + half * 64 + cq * 4) = p0;
        if (row0 + r + 16 < N)
            *(ushort4*)(h + (size_t)(row0 + r + 16) * 128 + half * 64 + cq * 4) = p1;
    }
}

// out1[n,:] = sum_{e in row n} dinv[n]*dinv[src]*h[src,:]; one wave per row.
// h rows are 256B bf16; each lane reads bf16x2 as one uint. 4-deep unroll.
__global__ __launch_bounds__(256) void k_pull1(const int* __restrict__ rs,
                                               const int* __restrict__ ssrc,
                                               const float* __restrict__ dinv,
                                               const uint32* __restrict__ h,
                                               float* __restrict__ out1, int N) {
    int n = (blockIdx.x * 256 + threadIdx.x) >> 6;
    if (n >= N) return;
    int lane = threadIdx.x & 63;
    int start = __builtin_amdgcn_readfirstlane((n == 0) ? 0 : rs[n - 1]);
    int end   = __builtin_amdgcn_readfirstlane(rs[n]);
    float dn = dinv[n];
    float2 a0 = {0.f, 0.f}, a1 = {0.f, 0.f}, a2 = {0.f, 0.f}, a3 = {0.f, 0.f};
    int j = start;
    for (; j + 3 < end; j += 4) {
        int s0 = __builtin_amdgcn_readfirstlane(ssrc[j]);
        int s1 = __builtin_amdgcn_readfirstlane(ssrc[j + 1]);
        int s2 = __builtin_amdgcn_readfirstlane(ssrc[j + 2]);
        int s3 = __builtin_amdgcn_readfirstlane(ssrc[j + 3]);
        uint32 u0 = h[(size_t)s0 * 64 + lane];
        uint32 u1 = h[(size_t)s1 * 64 + lane];
        uint32 u2 = h[(size_t)s2 * 64 + lane];
        uint32 u3 = h[(size_t)s3 * 64 + lane];
        float w0 = dn * dinv[s0];
        float w1 = dn * dinv[s1];
        float w2 = dn * dinv[s2];
        float w3 = dn * dinv[s3];
        bffma(a0, w0, u0);
        bffma(a1, w1, u1);
        bffma(a2, w2, u2);
        bffma(a3, w3, u3);
    }
    for (; j < end; ++j) {
        int s0 = __builtin_amdgcn_readfirstlane(ssrc[j]);
        uint32 u0 = h[(size_t)s0 * 64 + lane];
        bffma(a0, dn * dinv[s0], u0);
    }
    float2 r;
    r.x = (a0.x + a1.x) + (a2.x + a3.x);
    r.y = (a0.y + a1.y) + (a2.y + a3.y);
    ((float2*)out1)[(size_t)n * 64 + lane] = r;
}

// h2[N,16](bf16) = relu(out1 + b1) @ W2[128,16]; 32-row tile, 2 rows/thread.
__global__ __launch_bounds__(256) void k_gemm2(const float* __restrict__ out1,
                                               const float* __restrict__ b1,
                                               const float* __restrict__ W2,
                                               ushort16* __restrict__ h2, int N) {
    __shared__ float W2T[16 * 132];  // [f][k], pitch 132
    __shared__ float b1l[128];
    __shared__ float al[32 * 132];   // 32 rows, pitch 132
    int t = threadIdx.x;
    int row0 = blockIdx.x * 32;

    for (int g = t; g < 2048; g += 256) {
        int k = g >> 4, f = g & 15;
        W2T[f * 132 + k] = W2[g];
    }
    if (t < 128) b1l[t] = b1[t];
    __syncthreads();

    float4* al4 = (float4*)al;
    const float4* o4 = (const float4*)out1;
    const float4* b14 = (const float4*)b1l;
    for (int g = t; g < 32 * 32; g += 256) {
        int r = g >> 5, k4 = g & 31;
        float4 v = {0.f, 0.f, 0.f, 0.f};
        if (row0 + r < N) v = o4[(size_t)(row0 + r) * 32 + k4];
        float4 b = b14[k4];
        v.x = fmaxf(v.x + b.x, 0.f);
        v.y = fmaxf(v.y + b.y, 0.f);
        v.z = fmaxf(v.z + b.z, 0.f);
        v.w = fmaxf(v.w + b.w, 0.f);
        al4[r * 33 + k4] = v;
    }
    __syncthreads();

    int f = t & 15, r0 = t >> 4;
    const float4* W4 = (const float4*)W2T;
    float acc0 = 0.f, acc1 = 0.f;
    #pragma unroll 8
    for (int k4 = 0; k4 < 32; ++k4) {
        float4 w  = W4[f * 33 + k4];
        float4 x0 = al4[r0 * 33 + k4];
        float4 x1 = al4[(r0 + 16) * 33 + k4];
        acc0 = fmaf(x0.x, w.x, acc0); acc0 = fmaf(x0.y, w.y, acc0);
        acc0 = fmaf(x0.z, w.z, acc0); acc0 = fmaf(x0.w, w.w, acc0);
        acc1 = fmaf(x1.x, w.x, acc1); acc1 = fmaf(x1.y, w.y, acc1);
        acc1 = fmaf(x1.z, w.z, acc1); acc1 = fmaf(x1.w, w.w, acc1);
    }
    if (row0 + r0 < N)      h2[(size_t)(row0 + r0) * 16 + f] = bf16rn(acc0);
    if (row0 + r0 + 16 < N) h2[(size_t)(row0 + r0 + 16) * 16 + f] = bf16rn(acc1);
}

// out[n,:] = log_softmax( b2 + sum_e dinv[n]*dinv[src]*h2[src,:] )
// 8 lanes per row, 2 classes per lane (bf16x2 loads); 8-lane shuffle softmax.
__global__ __launch_bounds__(256) void k_pull2(const int* __restrict__ rs,
                                               const int* __restrict__ ssrc,
                                               const float* __restrict__ dinv,
                                               const uint32* __restrict__ h2,
                                               const float* __restrict__ b2,
                                               float* __restrict__ out, int N) {
    int idx = blockIdx.x * 256 + threadIdx.x;
    int n = idx >> 3;
    if (n >= N) return;
    int c = idx & 7;  // classes 2c, 2c+1
    int start = (n == 0) ? 0 : rs[n - 1];
    int end = rs[n];
    float dn = dinv[n];
    float acc0 = 0.f, acc1 = 0.f;
    for (int j = start; j < end; ++j) {
        int s = ssrc[j];
        float w = dn * dinv[s];
        uint32 u = h2[(size_t)s * 8 + c];
        acc0 = fmaf(w, __uint_as_float(u << 16), acc0);
        acc1 = fmaf(w, __uint_as_float(u & 0xffff0000u), acc1);
    }
    float v0 = acc0 + b2[2 * c];
    float v1 = acc1 + b2[2 * c + 1];
    float m = fmaxf(v0, v1);
    #pragma unroll
    for (int off = 1; off < 8; off <<= 1) m = fmaxf(m, __shfl_xor(m, off));
    float s = expf(v0 - m) + expf(v1 - m);
    #pragma unroll
    for (int off = 1; off < 8; off <<= 1) s += __shfl_xor(s, off);
    float ls = logf(s);
    float2 r = {v0 - m - ls, v1 - m - ls};
    ((float2*)out)[(size_t)n * 8 + c] = r;
}

extern "C" void kernel_launch(void* const* d_in, const int* in_sizes, int n_in,
                              void* d_out, int out_size, void* d_ws, size_t ws_size,
                              hipStream_t stream) {
    const float* x  = (const float*)d_in[0];
    const int*   ei = (const int*)d_in[1];
    const float* W1 = (const float*)d_in[2];
    const float* b1 = (const float*)d_in[3];
    const float* W2 = (const float*)d_in[4];
    const float* b2 = (const float*)d_in[5];
    float* out = (float*)d_out;

    const int E = in_sizes[1] / 2;
    const int N = in_sizes[0] / 128;
    const int* src  = ei;
    const int* dstv = ei + E;

    const int Npad = (N + 255) & ~255;
    int*   cnt  = (int*)d_ws;
    int*   rs   = cnt + Npad;
    int*   aux  = rs + Npad;
    float* dinv = (float*)(aux + 256);
    int*   ssrc = (int*)(dinv + Npad);
    ushort16* h = (ushort16*)(ssrc + ((E + 255) & ~255));  // N*128 bf16
    float* out1 = (float*)(h + (size_t)N * 128);           // N*128 f32
    ushort16* h2 = (ushort16*)h;                           // reuse, N*16 bf16

    const int nbN = (N + 255) / 256;
    const int nbE = (E + 255) / 256;

    hipMemsetAsync(cnt, 0, (size_t)N * sizeof(int), stream);
    k_count<<<nbE, 256, 0, stream>>>(dstv, cnt, E);
    k_dinv<<<nbN, 256, 0, stream>>>(cnt, dinv, N);
    k_scan1<<<nbN, 256, 0, stream>>>(cnt, rs, aux, N);
    k_scan2<<<1, 256, 0, stream>>>(aux, nbN);
    k_scan3<<<nbN, 256, 0, stream>>>(rs, aux, N);
    k_place<<<nbE, 256, 0, stream>>>(src, dstv, rs, ssrc, E);

    k_gemm1<<<(N + 31) / 32, 256, 0, stream>>>(x, W1, h, N);

    k_pull1<<<(N * 64 + 255) / 256, 256, 0, stream>>>(rs, ssrc, dinv,
                                                      (const uint32*)h, out1, N);

    k_gemm2<<<(N + 31) / 32, 256, 0, stream>>>(out1, b1, W2, h2, N);

    k_pull2<<<(N * 8 + 255) / 256, 256, 0, stream>>>(rs, ssrc, dinv,
                                                     (const uint32*)h2, b2, out, N);
}

// Round 5
// 219.429 us; speedup vs baseline: 2.8501x; 1.2292x over previous
//
#include <hip/hip_runtime.h>

// GCN 2-layer forward — pull-based aggregation, bf16 gather payloads.
// R5: preprocessing rebuilt as 2-level LDS-staged counting sort
//     (hist -> scanB -> partition -> bsort). Every ssrc/tmp line is written
//     by exactly ONE block => no cross-XCD line ping-pong (k_place wrote
//     54 MB HBM for a 3.4 MB array; predicted ~7 MB now).
// Buckets: 256 nodes each (bucket = dst >> 8), NB = ceil(N/256) <= 1024.

typedef unsigned int uint32;
typedef unsigned short ushort16;

#define NBMAX 1024
#define CHUNK 4096

__device__ inline void fma4(float4& a, float s, const float4& w) {
    a.x = fmaf(s, w.x, a.x);
    a.y = fmaf(s, w.y, a.y);
    a.z = fmaf(s, w.z, a.z);
    a.w = fmaf(s, w.w, a.w);
}

__device__ inline unsigned short bf16rn(float f) {
    unsigned u = __float_as_uint(f);
    return (unsigned short)((u + 0x7fffu + ((u >> 16) & 1u)) >> 16);
}

__device__ inline void bffma(float2& a, float w, uint32 u) {
    a.x = fmaf(w, __uint_as_float(u << 16), a.x);
    a.y = fmaf(w, __uint_as_float(u & 0xffff0000u), a.y);
}

// --- preprocessing: counting sort of edges by dst ---------------------------

// coarse bucket histogram, LDS-staged
__global__ __launch_bounds__(256) void k_hist(const int* __restrict__ dst,
                                              int* __restrict__ bcnt,
                                              int E, int NB) {
    __shared__ int hl[NBMAX];
    int t = threadIdx.x;
    for (int i = t; i < NB; i += 256) hl[i] = 0;
    __syncthreads();
    int stride = gridDim.x * 256;
    for (int e = blockIdx.x * 256 + t; e < E; e += stride)
        atomicAdd(&hl[dst[e] >> 8], 1);
    __syncthreads();
    for (int i = t; i < NB; i += 256)
        if (hl[i]) atomicAdd(&bcnt[i], hl[i]);
}

// exclusive scan of bucket counts; also zero fill counters
__global__ __launch_bounds__(1024) void k_scanB(const int* __restrict__ bcnt,
                                                int* __restrict__ bbase,
                                                int* __restrict__ bfill,
                                                int NB, int E) {
    __shared__ int s[1024];
    int t = threadIdx.x;
    int v = (t < NB) ? bcnt[t] : 0;
    s[t] = v;
    __syncthreads();
    for (int off = 1; off < 1024; off <<= 1) {
        int u = (t >= off) ? s[t - off] : 0;
        __syncthreads();
        s[t] += u;
        __syncthreads();
    }
    if (t < NB) {
        bbase[t] = s[t] - v;
        bfill[t] = 0;
    }
    if (t == 0) bbase[NB] = E;
}

// partition edges into bucket regions; per-(block,bucket) contiguous runs
__global__ __launch_bounds__(256) void k_partition(const int* __restrict__ src,
                                                   const int* __restrict__ dst,
                                                   const int* __restrict__ bbase,
                                                   int* __restrict__ bfill,
                                                   int2* __restrict__ tmp,
                                                   int E, int NB) {
    __shared__ int cntL[NBMAX];
    __shared__ int baseL[NBMAX];
    int t = threadIdx.x;
    int e0 = blockIdx.x * CHUNK;
    int e1 = min(e0 + CHUNK, E);
    for (int i = t; i < NB; i += 256) cntL[i] = 0;
    __syncthreads();
    for (int e = e0 + t; e < e1; e += 256)
        atomicAdd(&cntL[dst[e] >> 8], 1);
    __syncthreads();
    for (int i = t; i < NB; i += 256) {
        int c = cntL[i];
        baseL[i] = c ? bbase[i] + atomicAdd(&bfill[i], c) : 0;
        cntL[i] = 0;
    }
    __syncthreads();
    for (int e = e0 + t; e < e1; e += 256) {
        int s = src[e], d = dst[e];
        int b = d >> 8;
        int r = atomicAdd(&cntL[b], 1);
        tmp[baseL[b] + r] = make_int2(s, d);
    }
}

// one block per bucket: exact per-node counts, scan, emit dinv/rs/sorted ssrc
__global__ __launch_bounds__(256) void k_bsort(const int2* __restrict__ tmp,
                                               const int* __restrict__ bbase,
                                               int* __restrict__ ssrc,
                                               int* __restrict__ rs,
                                               float* __restrict__ dinv,
                                               int N) {
    __shared__ int cnt[256];
    __shared__ int ofs[256];
    int t = threadIdx.x;
    int b = blockIdx.x;
    int base = bbase[b];
    int endb = bbase[b + 1];
    int node0 = b << 8;

    cnt[t] = 0;
    __syncthreads();
    for (int i = base + t; i < endb; i += 256)
        atomicAdd(&cnt[tmp[i].y & 255], 1);
    __syncthreads();

    int v = cnt[t];
    __syncthreads();
    // Hillis-Steele inclusive scan over 256
    for (int off = 1; off < 256; off <<= 1) {
        int u = (t >= off) ? cnt[t - off] : 0;
        __syncthreads();
        cnt[t] += u;
        __syncthreads();
    }
    int node = node0 + t;
    if (node < N) {
        dinv[node] = rsqrtf(fmaxf((float)v, 1.0f));
        rs[node] = base + cnt[t];           // inclusive end of row `node`
    }
    ofs[t] = base + cnt[t] - v;             // exclusive start
    __syncthreads();

    for (int i = base + t; i < endb; i += 256) {
        int2 rec = tmp[i];
        int pos = atomicAdd(&ofs[rec.y & 255], 1);
        ssrc[pos] = rec.x;
    }
}

// --- compute kernels --------------------------------------------------------

// h[N,128](bf16) = x[N,128] @ W1[128,128]; 32-row tile, W1 in 2 col-halves.
__global__ __launch_bounds__(256) void k_gemm1(const float* __restrict__ x,
                                               const float* __restrict__ W,
                                               ushort16* __restrict__ h, int N) {
    __shared__ float Wl[128 * 64];
    __shared__ float xl[32 * 132];
    int t = threadIdx.x;
    int row0 = blockIdx.x * 32;

    float4* xl4 = (float4*)xl;
    const float4* xg4 = (const float4*)x;
    for (int g = t; g < 32 * 32; g += 256) {
        int r = g >> 5, k4 = g & 31;
        float4 v = {0.f, 0.f, 0.f, 0.f};
        if (row0 + r < N) v = xg4[(size_t)(row0 + r) * 32 + k4];
        xl4[r * 33 + k4] = v;
    }

    float4* Wl4 = (float4*)Wl;
    const float4* Wg4 = (const float4*)W;
    int r = t >> 4;
    int cq = t & 15;

    for (int half = 0; half < 2; ++half) {
        __syncthreads();
        for (int g = t; g < 128 * 16; g += 256) {
            int k = g >> 4, c4 = g & 15;
            Wl4[k * 16 + c4] = Wg4[k * 32 + half * 16 + c4];
        }
        __syncthreads();

        float4 a0 = {0.f, 0.f, 0.f, 0.f}, a1 = {0.f, 0.f, 0.f, 0.f};
        #pragma unroll 8
        for (int k4 = 0; k4 < 32; ++k4) {
            float4 xv0 = xl4[r * 33 + k4];
            float4 xv1 = xl4[(r + 16) * 33 + k4];
            float4 w0 = Wl4[(k4 * 4 + 0) * 16 + cq];
            float4 w1 = Wl4[(k4 * 4 + 1) * 16 + cq];
            float4 w2 = Wl4[(k4 * 4 + 2) * 16 + cq];
            float4 w3 = Wl4[(k4 * 4 + 3) * 16 + cq];
            fma4(a0, xv0.x, w0); fma4(a0, xv0.y, w1);
            fma4(a0, xv0.z, w2); fma4(a0, xv0.w, w3);
            fma4(a1, xv1.x, w0); fma4(a1, xv1.y, w1);
            fma4(a1, xv1.z, w2); fma4(a1, xv1.w, w3);
        }
        ushort4 p0, p1;
        p0.x = bf16rn(a0.x); p0.y = bf16rn(a0.y); p0.z = bf16rn(a0.z); p0.w = bf16rn(a0.w);
        p1.x = bf16rn(a1.x); p1.y = bf16rn(a1.y); p1.z = bf16rn(a1.z); p1.w = bf16rn(a1.w);
        if (row0 + r < N)
            *(ushort4*)(h + (size_t)(row0 + r) * 128 + half * 64 + cq * 4) = p0;
        if (row0 + r + 16 < N)
            *(ushort4*)(h + (size_t)(row0 + r + 16) * 128 + half * 64 + cq * 4) = p1;
    }
}

// out1[n,:] = sum_{e in row n} dinv[n]*dinv[src]*h[src,:]; one wave per row.
__global__ __launch_bounds__(256) void k_pull1(const int* __restrict__ rs,
                                               const int* __restrict__ ssrc,
                                               const float* __restrict__ dinv,
                                               const uint32* __restrict__ h,
                                               float* __restrict__ out1, int N) {
    int n = (blockIdx.x * 256 + threadIdx.x) >> 6;
    if (n >= N) return;
    int lane = threadIdx.x & 63;
    int start = __builtin_amdgcn_readfirstlane((n == 0) ? 0 : rs[n - 1]);
    int end   = __builtin_amdgcn_readfirstlane(rs[n]);
    float dn = dinv[n];
    float2 a0 = {0.f, 0.f}, a1 = {0.f, 0.f}, a2 = {0.f, 0.f}, a3 = {0.f, 0.f};
    int j = start;
    for (; j + 3 < end; j += 4) {
        int s0 = __builtin_amdgcn_readfirstlane(ssrc[j]);
        int s1 = __builtin_amdgcn_readfirstlane(ssrc[j + 1]);
        int s2 = __builtin_amdgcn_readfirstlane(ssrc[j + 2]);
        int s3 = __builtin_amdgcn_readfirstlane(ssrc[j + 3]);
        uint32 u0 = h[(size_t)s0 * 64 + lane];
        uint32 u1 = h[(size_t)s1 * 64 + lane];
        uint32 u2 = h[(size_t)s2 * 64 + lane];
        uint32 u3 = h[(size_t)s3 * 64 + lane];
        float w0 = dn * dinv[s0];
        float w1 = dn * dinv[s1];
        float w2 = dn * dinv[s2];
        float w3 = dn * dinv[s3];
        bffma(a0, w0, u0);
        bffma(a1, w1, u1);
        bffma(a2, w2, u2);
        bffma(a3, w3, u3);
    }
    for (; j < end; ++j) {
        int s0 = __builtin_amdgcn_readfirstlane(ssrc[j]);
        uint32 u0 = h[(size_t)s0 * 64 + lane];
        bffma(a0, dn * dinv[s0], u0);
    }
    float2 r;
    r.x = (a0.x + a1.x) + (a2.x + a3.x);
    r.y = (a0.y + a1.y) + (a2.y + a3.y);
    ((float2*)out1)[(size_t)n * 64 + lane] = r;
}

// h2[N,16](bf16) = relu(out1 + b1) @ W2[128,16]; 32-row tile, 2 rows/thread.
__global__ __launch_bounds__(256) void k_gemm2(const float* __restrict__ out1,
                                               const float* __restrict__ b1,
                                               const float* __restrict__ W2,
                                               ushort16* __restrict__ h2, int N) {
    __shared__ float W2T[16 * 132];
    __shared__ float b1l[128];
    __shared__ float al[32 * 132];
    int t = threadIdx.x;
    int row0 = blockIdx.x * 32;

    for (int g = t; g < 2048; g += 256) {
        int k = g >> 4, f = g & 15;
        W2T[f * 132 + k] = W2[g];
    }
    if (t < 128) b1l[t] = b1[t];
    __syncthreads();

    float4* al4 = (float4*)al;
    const float4* o4 = (const float4*)out1;
    const float4* b14 = (const float4*)b1l;
    for (int g = t; g < 32 * 32; g += 256) {
        int r = g >> 5, k4 = g & 31;
        float4 v = {0.f, 0.f, 0.f, 0.f};
        if (row0 + r < N) v = o4[(size_t)(row0 + r) * 32 + k4];
        float4 b = b14[k4];
        v.x = fmaxf(v.x + b.x, 0.f);
        v.y = fmaxf(v.y + b.y, 0.f);
        v.z = fmaxf(v.z + b.z, 0.f);
        v.w = fmaxf(v.w + b.w, 0.f);
        al4[r * 33 + k4] = v;
    }
    __syncthreads();

    int f = t & 15, r0 = t >> 4;
    const float4* W4 = (const float4*)W2T;
    float acc0 = 0.f, acc1 = 0.f;
    #pragma unroll 8
    for (int k4 = 0; k4 < 32; ++k4) {
        float4 w  = W4[f * 33 + k4];
        float4 x0 = al4[r0 * 33 + k4];
        float4 x1 = al4[(r0 + 16) * 33 + k4];
        acc0 = fmaf(x0.x, w.x, acc0); acc0 = fmaf(x0.y, w.y, acc0);
        acc0 = fmaf(x0.z, w.z, acc0); acc0 = fmaf(x0.w, w.w, acc0);
        acc1 = fmaf(x1.x, w.x, acc1); acc1 = fmaf(x1.y, w.y, acc1);
        acc1 = fmaf(x1.z, w.z, acc1); acc1 = fmaf(x1.w, w.w, acc1);
    }
    if (row0 + r0 < N)      h2[(size_t)(row0 + r0) * 16 + f] = bf16rn(acc0);
    if (row0 + r0 + 16 < N) h2[(size_t)(row0 + r0 + 16) * 16 + f] = bf16rn(acc1);
}

// out[n,:] = log_softmax( b2 + sum_e dinv[n]*dinv[src]*h2[src,:] )
// 8 lanes per row, 2 classes per lane; 8-lane shuffle softmax (fused).
__global__ __launch_bounds__(256) void k_pull2(const int* __restrict__ rs,
                                               const int* __restrict__ ssrc,
                                               const float* __restrict__ dinv,
                                               const uint32* __restrict__ h2,
                                               const float* __restrict__ b2,
                                               float* __restrict__ out, int N) {
    int idx = blockIdx.x * 256 + threadIdx.x;
    int n = idx >> 3;
    if (n >= N) return;
    int c = idx & 7;
    int start = (n == 0) ? 0 : rs[n - 1];
    int end = rs[n];
    float dn = dinv[n];
    float acc0 = 0.f, acc1 = 0.f;
    for (int j = start; j < end; ++j) {
        int s = ssrc[j];
        float w = dn * dinv[s];
        uint32 u = h2[(size_t)s * 8 + c];
        acc0 = fmaf(w, __uint_as_float(u << 16), acc0);
        acc1 = fmaf(w, __uint_as_float(u & 0xffff0000u), acc1);
    }
    float v0 = acc0 + b2[2 * c];
    float v1 = acc1 + b2[2 * c + 1];
    float m = fmaxf(v0, v1);
    #pragma unroll
    for (int off = 1; off < 8; off <<= 1) m = fmaxf(m, __shfl_xor(m, off));
    float s = expf(v0 - m) + expf(v1 - m);
    #pragma unroll
    for (int off = 1; off < 8; off <<= 1) s += __shfl_xor(s, off);
    float ls = logf(s);
    float2 r = {v0 - m - ls, v1 - m - ls};
    ((float2*)out)[(size_t)n * 8 + c] = r;
}

extern "C" void kernel_launch(void* const* d_in, const int* in_sizes, int n_in,
                              void* d_out, int out_size, void* d_ws, size_t ws_size,
                              hipStream_t stream) {
    const float* x  = (const float*)d_in[0];
    const int*   ei = (const int*)d_in[1];
    const float* W1 = (const float*)d_in[2];
    const float* b1 = (const float*)d_in[3];
    const float* W2 = (const float*)d_in[4];
    const float* b2 = (const float*)d_in[5];
    float* out = (float*)d_out;

    const int E = in_sizes[1] / 2;
    const int N = in_sizes[0] / 128;
    const int NB = (N + 255) >> 8;
    const int* src  = ei;
    const int* dstv = ei + E;

    const int Npad = (N + 255) & ~255;
    const int Epad = (E + 255) & ~255;
    int*   bcnt  = (int*)d_ws;                 // [NBMAX]
    int*   bbase = bcnt + NBMAX;               // [NBMAX+1] (+pad)
    int*   bfill = bbase + NBMAX + 256;        // [NBMAX]
    int*   rs    = bfill + NBMAX;              // [Npad]
    float* dinv  = (float*)(rs + Npad);        // [Npad]
    int2*  tmp   = (int2*)(dinv + Npad);       // [Epad] (8B aligned)
    int*   ssrc  = (int*)(tmp + Epad);         // [Epad]
    ushort16* h  = (ushort16*)(ssrc + Epad);   // N*128 bf16
    float* out1  = (float*)(h + (size_t)N * 128);
    ushort16* h2 = (ushort16*)h;               // reuse after pull1

    hipMemsetAsync(bcnt, 0, NBMAX * sizeof(int), stream);
    k_hist<<<512, 256, 0, stream>>>(dstv, bcnt, E, NB);
    k_scanB<<<1, 1024, 0, stream>>>(bcnt, bbase, bfill, NB, E);
    k_partition<<<(E + CHUNK - 1) / CHUNK, 256, 0, stream>>>(src, dstv, bbase,
                                                             bfill, tmp, E, NB);
    k_bsort<<<NB, 256, 0, stream>>>(tmp, bbase, ssrc, rs, dinv, N);

    k_gemm1<<<(N + 31) / 32, 256, 0, stream>>>(x, W1, h, N);

    k_pull1<<<(N * 64 + 255) / 256, 256, 0, stream>>>(rs, ssrc, dinv,
                                                      (const uint32*)h, out1, N);

    k_gemm2<<<(N + 31) / 32, 256, 0, stream>>>(out1, b1, W2, h2, N);

    k_pull2<<<(N * 8 + 255) / 256, 256, 0, stream>>>(rs, ssrc, dinv,
                                                     (const uint32*)h2, b2, out, N);
}

// Round 6
// 202.820 us; speedup vs baseline: 3.0835x; 1.0819x over previous
//
#include <hip/hip_runtime.h>

// GCN 2-layer forward — pull-based aggregation, bf16 gather payloads.
// R6: gemm1 -> MFMA 16x16x32 bf16 (compute was VALU-bound ~28us; now memory
//     floor ~11us). out1 stored packed bf16x2 (halves pull1 write + gemm2 read).
// Preprocessing: 2-level LDS counting sort (hist->scanB->partition->bsort).

typedef unsigned int uint32;
typedef unsigned short ushort16;  // scalar ushort (legacy name)
typedef __attribute__((ext_vector_type(8))) short bf16x8;
typedef __attribute__((ext_vector_type(4))) float f32x4;

#define NBMAX 1024
#define CHUNK 4096

__device__ inline unsigned short bf16rn(float f) {
    unsigned u = __float_as_uint(f);
    return (unsigned short)((u + 0x7fffu + ((u >> 16) & 1u)) >> 16);
}

__device__ inline void bffma(float2& a, float w, uint32 u) {
    a.x = fmaf(w, __uint_as_float(u << 16), a.x);
    a.y = fmaf(w, __uint_as_float(u & 0xffff0000u), a.y);
}

// --- preprocessing: counting sort of edges by dst ---------------------------

__global__ __launch_bounds__(256) void k_hist(const int* __restrict__ dst,
                                              int* __restrict__ bcnt,
                                              int E, int NB) {
    __shared__ int hl[NBMAX];
    int t = threadIdx.x;
    for (int i = t; i < NB; i += 256) hl[i] = 0;
    __syncthreads();
    int stride = gridDim.x * 256;
    for (int e = blockIdx.x * 256 + t; e < E; e += stride)
        atomicAdd(&hl[dst[e] >> 8], 1);
    __syncthreads();
    for (int i = t; i < NB; i += 256)
        if (hl[i]) atomicAdd(&bcnt[i], hl[i]);
}

__global__ __launch_bounds__(1024) void k_scanB(const int* __restrict__ bcnt,
                                                int* __restrict__ bbase,
                                                int* __restrict__ bfill,
                                                int NB, int E) {
    __shared__ int s[1024];
    int t = threadIdx.x;
    int v = (t < NB) ? bcnt[t] : 0;
    s[t] = v;
    __syncthreads();
    for (int off = 1; off < 1024; off <<= 1) {
        int u = (t >= off) ? s[t - off] : 0;
        __syncthreads();
        s[t] += u;
        __syncthreads();
    }
    if (t < NB) {
        bbase[t] = s[t] - v;
        bfill[t] = 0;
    }
    if (t == 0) bbase[NB] = E;
}

__global__ __launch_bounds__(256) void k_partition(const int* __restrict__ src,
                                                   const int* __restrict__ dst,
                                                   const int* __restrict__ bbase,
                                                   int* __restrict__ bfill,
                                                   int2* __restrict__ tmp,
                                                   int E, int NB) {
    __shared__ int cntL[NBMAX];
    __shared__ int baseL[NBMAX];
    int t = threadIdx.x;
    int e0 = blockIdx.x * CHUNK;
    int e1 = min(e0 + CHUNK, E);
    for (int i = t; i < NB; i += 256) cntL[i] = 0;
    __syncthreads();
    for (int e = e0 + t; e < e1; e += 256)
        atomicAdd(&cntL[dst[e] >> 8], 1);
    __syncthreads();
    for (int i = t; i < NB; i += 256) {
        int c = cntL[i];
        baseL[i] = c ? bbase[i] + atomicAdd(&bfill[i], c) : 0;
        cntL[i] = 0;
    }
    __syncthreads();
    for (int e = e0 + t; e < e1; e += 256) {
        int s = src[e], d = dst[e];
        int b = d >> 8;
        int r = atomicAdd(&cntL[b], 1);
        tmp[baseL[b] + r] = make_int2(s, d);
    }
}

__global__ __launch_bounds__(256) void k_bsort(const int2* __restrict__ tmp,
                                               const int* __restrict__ bbase,
                                               int* __restrict__ ssrc,
                                               int* __restrict__ rs,
                                               float* __restrict__ dinv,
                                               int N) {
    __shared__ int cnt[256];
    __shared__ int ofs[256];
    int t = threadIdx.x;
    int b = blockIdx.x;
    int base = bbase[b];
    int endb = bbase[b + 1];
    int node0 = b << 8;

    cnt[t] = 0;
    __syncthreads();
    for (int i = base + t; i < endb; i += 256)
        atomicAdd(&cnt[tmp[i].y & 255], 1);
    __syncthreads();

    int v = cnt[t];
    __syncthreads();
    for (int off = 1; off < 256; off <<= 1) {
        int u = (t >= off) ? cnt[t - off] : 0;
        __syncthreads();
        cnt[t] += u;
        __syncthreads();
    }
    int node = node0 + t;
    if (node < N) {
        dinv[node] = rsqrtf(fmaxf((float)v, 1.0f));
        rs[node] = base + cnt[t];
    }
    ofs[t] = base + cnt[t] - v;
    __syncthreads();

    for (int i = base + t; i < endb; i += 256) {
        int2 rec = tmp[i];
        int pos = atomicAdd(&ofs[rec.y & 255], 1);
        ssrc[pos] = rec.x;
    }
}

// --- compute kernels --------------------------------------------------------

// h[N,128](bf16) = x[N,128] @ W1[128,128] via MFMA 16x16x32 bf16.
// 64 rows/block (4 waves x 16 rows); W1 staged bf16 in LDS [n][k] pitch 136
// (272B row stride -> 2-way bank aliasing = free). A-frag direct from global
// with cvt. C layout: col=lane&15, row=quad*4+reg.
__global__ __launch_bounds__(256) void k_gemm1(const float* __restrict__ x,
                                               const float* __restrict__ W,
                                               ushort16* __restrict__ h, int N) {
    __shared__ unsigned short Wl[128 * 136];
    int t = threadIdx.x;
    const float4* Wg4 = (const float4*)W;
    for (int g = t; g < 128 * 32; g += 256) {
        int k = g >> 5, n4 = (g & 31) * 4;
        float4 v = Wg4[g];
        Wl[(n4 + 0) * 136 + k] = bf16rn(v.x);
        Wl[(n4 + 1) * 136 + k] = bf16rn(v.y);
        Wl[(n4 + 2) * 136 + k] = bf16rn(v.z);
        Wl[(n4 + 3) * 136 + k] = bf16rn(v.w);
    }
    __syncthreads();

    int wave = t >> 6, lane = t & 63;
    int quad = lane >> 4, ln = lane & 15;
    int rowbase = blockIdx.x * 64 + wave * 16;
    int arow = rowbase + ln;                  // A row for this lane
    int rclamp = min(arow, N - 1);

    f32x4 acc[8];
    #pragma unroll
    for (int ct = 0; ct < 8; ++ct) acc[ct] = (f32x4){0.f, 0.f, 0.f, 0.f};

    #pragma unroll
    for (int q = 0; q < 4; ++q) {
        const float4* xr = (const float4*)(x + (size_t)rclamp * 128 + q * 32 + quad * 8);
        float4 a0 = xr[0], a1 = xr[1];
        bf16x8 afr;
        afr[0] = (short)bf16rn(a0.x); afr[1] = (short)bf16rn(a0.y);
        afr[2] = (short)bf16rn(a0.z); afr[3] = (short)bf16rn(a0.w);
        afr[4] = (short)bf16rn(a1.x); afr[5] = (short)bf16rn(a1.y);
        afr[6] = (short)bf16rn(a1.z); afr[7] = (short)bf16rn(a1.w);
        #pragma unroll
        for (int ct = 0; ct < 8; ++ct) {
            bf16x8 bfr = *(const bf16x8*)&Wl[(ct * 16 + ln) * 136 + q * 32 + quad * 8];
            acc[ct] = __builtin_amdgcn_mfma_f32_16x16x32_bf16(afr, bfr, acc[ct], 0, 0, 0);
        }
    }

    #pragma unroll
    for (int i = 0; i < 4; ++i) {
        int r = rowbase + quad * 4 + i;
        if (r < N) {
            ushort16* hp = h + (size_t)r * 128 + ln;
            #pragma unroll
            for (int ct = 0; ct < 8; ++ct)
                hp[ct * 16] = bf16rn(acc[ct][i]);
        }
    }
}

// out1[n,:] (packed bf16x2) = sum_{e in row n} dinv[n]*dinv[src]*h[src,:]
// one wave per row; fp32 accumulate, bf16 store.
__global__ __launch_bounds__(256) void k_pull1(const int* __restrict__ rs,
                                               const int* __restrict__ ssrc,
                                               const float* __restrict__ dinv,
                                               const uint32* __restrict__ h,
                                               uint32* __restrict__ out1, int N) {
    int n = (blockIdx.x * 256 + threadIdx.x) >> 6;
    if (n >= N) return;
    int lane = threadIdx.x & 63;
    int start = __builtin_amdgcn_readfirstlane((n == 0) ? 0 : rs[n - 1]);
    int end   = __builtin_amdgcn_readfirstlane(rs[n]);
    float dn = dinv[n];
    float2 a0 = {0.f, 0.f}, a1 = {0.f, 0.f}, a2 = {0.f, 0.f}, a3 = {0.f, 0.f};
    int j = start;
    for (; j + 3 < end; j += 4) {
        int s0 = __builtin_amdgcn_readfirstlane(ssrc[j]);
        int s1 = __builtin_amdgcn_readfirstlane(ssrc[j + 1]);
        int s2 = __builtin_amdgcn_readfirstlane(ssrc[j + 2]);
        int s3 = __builtin_amdgcn_readfirstlane(ssrc[j + 3]);
        uint32 u0 = h[(size_t)s0 * 64 + lane];
        uint32 u1 = h[(size_t)s1 * 64 + lane];
        uint32 u2 = h[(size_t)s2 * 64 + lane];
        uint32 u3 = h[(size_t)s3 * 64 + lane];
        float w0 = dn * dinv[s0];
        float w1 = dn * dinv[s1];
        float w2 = dn * dinv[s2];
        float w3 = dn * dinv[s3];
        bffma(a0, w0, u0);
        bffma(a1, w1, u1);
        bffma(a2, w2, u2);
        bffma(a3, w3, u3);
    }
    for (; j < end; ++j) {
        int s0 = __builtin_amdgcn_readfirstlane(ssrc[j]);
        uint32 u0 = h[(size_t)s0 * 64 + lane];
        bffma(a0, dn * dinv[s0], u0);
    }
    float rx = (a0.x + a1.x) + (a2.x + a3.x);
    float ry = (a0.y + a1.y) + (a2.y + a3.y);
    out1[(size_t)n * 64 + lane] = ((uint32)bf16rn(ry) << 16) | bf16rn(rx);
}

// h2[N,16](bf16) = relu(out1 + b1) @ W2[128,16]; 32-row tile, 2 rows/thread.
// out1 is packed bf16x2 (64 uints/row).
__global__ __launch_bounds__(256) void k_gemm2(const uint32* __restrict__ out1,
                                               const float* __restrict__ b1,
                                               const float* __restrict__ W2,
                                               ushort16* __restrict__ h2, int N) {
    __shared__ float W2T[16 * 132];
    __shared__ float b1l[128];
    __shared__ float al[32 * 132];
    int t = threadIdx.x;
    int row0 = blockIdx.x * 32;

    for (int g = t; g < 2048; g += 256) {
        int k = g >> 4, f = g & 15;
        W2T[f * 132 + k] = W2[g];
    }
    if (t < 128) b1l[t] = b1[t];
    __syncthreads();

    float4* al4 = (float4*)al;
    const uint4* o4 = (const uint4*)out1;
    for (int g = t; g < 32 * 16; g += 256) {
        int r = g >> 4, k8 = g & 15;  // 8 cols at k8*8
        uint4 u = {0u, 0u, 0u, 0u};
        if (row0 + r < N) u = o4[(size_t)(row0 + r) * 16 + k8];
        const float* bb = &b1l[k8 * 8];
        float4 v0, v1;
        v0.x = fmaxf(__uint_as_float(u.x << 16)          + bb[0], 0.f);
        v0.y = fmaxf(__uint_as_float(u.x & 0xffff0000u)  + bb[1], 0.f);
        v0.z = fmaxf(__uint_as_float(u.y << 16)          + bb[2], 0.f);
        v0.w = fmaxf(__uint_as_float(u.y & 0xffff0000u)  + bb[3], 0.f);
        v1.x = fmaxf(__uint_as_float(u.z << 16)          + bb[4], 0.f);
        v1.y = fmaxf(__uint_as_float(u.z & 0xffff0000u)  + bb[5], 0.f);
        v1.z = fmaxf(__uint_as_float(u.w << 16)          + bb[6], 0.f);
        v1.w = fmaxf(__uint_as_float(u.w & 0xffff0000u)  + bb[7], 0.f);
        al4[r * 33 + k8 * 2]     = v0;
        al4[r * 33 + k8 * 2 + 1] = v1;
    }
    __syncthreads();

    int f = t & 15, r0 = t >> 4;
    const float4* W4 = (const float4*)W2T;
    float acc0 = 0.f, acc1 = 0.f;
    #pragma unroll 8
    for (int k4 = 0; k4 < 32; ++k4) {
        float4 w  = W4[f * 33 + k4];
        float4 x0 = al4[r0 * 33 + k4];
        float4 x1 = al4[(r0 + 16) * 33 + k4];
        acc0 = fmaf(x0.x, w.x, acc0); acc0 = fmaf(x0.y, w.y, acc0);
        acc0 = fmaf(x0.z, w.z, acc0); acc0 = fmaf(x0.w, w.w, acc0);
        acc1 = fmaf(x1.x, w.x, acc1); acc1 = fmaf(x1.y, w.y, acc1);
        acc1 = fmaf(x1.z, w.z, acc1); acc1 = fmaf(x1.w, w.w, acc1);
    }
    if (row0 + r0 < N)      h2[(size_t)(row0 + r0) * 16 + f] = bf16rn(acc0);
    if (row0 + r0 + 16 < N) h2[(size_t)(row0 + r0 + 16) * 16 + f] = bf16rn(acc1);
}

// out[n,:] = log_softmax( b2 + sum_e dinv[n]*dinv[src]*h2[src,:] )
// 8 lanes per row, 2 classes per lane; 8-lane shuffle softmax (fused).
__global__ __launch_bounds__(256) void k_pull2(const int* __restrict__ rs,
                                               const int* __restrict__ ssrc,
                                               const float* __restrict__ dinv,
                                               const uint32* __restrict__ h2,
                                               const float* __restrict__ b2,
                                               float* __restrict__ out, int N) {
    int idx = blockIdx.x * 256 + threadIdx.x;
    int n = idx >> 3;
    if (n >= N) return;
    int c = idx & 7;
    int start = (n == 0) ? 0 : rs[n - 1];
    int end = rs[n];
    float dn = dinv[n];
    float acc0 = 0.f, acc1 = 0.f;
    for (int j = start; j < end; ++j) {
        int s = ssrc[j];
        float w = dn * dinv[s];
        uint32 u = h2[(size_t)s * 8 + c];
        acc0 = fmaf(w, __uint_as_float(u << 16), acc0);
        acc1 = fmaf(w, __uint_as_float(u & 0xffff0000u), acc1);
    }
    float v0 = acc0 + b2[2 * c];
    float v1 = acc1 + b2[2 * c + 1];
    float m = fmaxf(v0, v1);
    #pragma unroll
    for (int off = 1; off < 8; off <<= 1) m = fmaxf(m, __shfl_xor(m, off));
    float s = expf(v0 - m) + expf(v1 - m);
    #pragma unroll
    for (int off = 1; off < 8; off <<= 1) s += __shfl_xor(s, off);
    float ls = logf(s);
    float2 r = {v0 - m - ls, v1 - m - ls};
    ((float2*)out)[(size_t)n * 8 + c] = r;
}

extern "C" void kernel_launch(void* const* d_in, const int* in_sizes, int n_in,
                              void* d_out, int out_size, void* d_ws, size_t ws_size,
                              hipStream_t stream) {
    const float* x  = (const float*)d_in[0];
    const int*   ei = (const int*)d_in[1];
    const float* W1 = (const float*)d_in[2];
    const float* b1 = (const float*)d_in[3];
    const float* W2 = (const float*)d_in[4];
    const float* b2 = (const float*)d_in[5];
    float* out = (float*)d_out;

    const int E = in_sizes[1] / 2;
    const int N = in_sizes[0] / 128;
    const int NB = (N + 255) >> 8;
    const int* src  = ei;
    const int* dstv = ei + E;

    const int Npad = (N + 255) & ~255;
    const int Epad = (E + 255) & ~255;
    int*   bcnt  = (int*)d_ws;                 // [NBMAX]
    int*   bbase = bcnt + NBMAX;               // [NBMAX+1] (+pad)
    int*   bfill = bbase + NBMAX + 256;        // [NBMAX]
    int*   rs    = bfill + NBMAX;              // [Npad]
    float* dinv  = (float*)(rs + Npad);        // [Npad]
    int2*  tmp   = (int2*)(dinv + Npad);       // [Epad]
    int*   ssrc  = (int*)(tmp + Epad);         // [Epad]
    ushort16* h  = (ushort16*)(ssrc + Epad);   // N*128 bf16
    uint32* out1 = (uint32*)(h + (size_t)N * 128);  // N*64 packed bf16x2
    ushort16* h2 = (ushort16*)h;               // reuse after pull1

    hipMemsetAsync(bcnt, 0, NBMAX * sizeof(int), stream);
    k_hist<<<512, 256, 0, stream>>>(dstv, bcnt, E, NB);
    k_scanB<<<1, 1024, 0, stream>>>(bcnt, bbase, bfill, NB, E);
    k_partition<<<(E + CHUNK - 1) / CHUNK, 256, 0, stream>>>(src, dstv, bbase,
                                                             bfill, tmp, E, NB);
    k_bsort<<<NB, 256, 0, stream>>>(tmp, bbase, ssrc, rs, dinv, N);

    k_gemm1<<<(N + 63) / 64, 256, 0, stream>>>(x, W1, h, N);

    k_pull1<<<(N * 64 + 255) / 256, 256, 0, stream>>>(rs, ssrc, dinv,
                                                      (const uint32*)h, out1, N);

    k_gemm2<<<(N + 31) / 32, 256, 0, stream>>>(out1, b1, W2, h2, N);

    k_pull2<<<(N * 8 + 255) / 256, 256, 0, stream>>>(rs, ssrc, dinv,
                                                     (const uint32*)h2, b2, out, N);
}